// Round 11
// baseline (128.737 us; speedup 1.0000x reference)
//
#include <hip/hip_runtime.h>
#include <math.h>

#ifndef __has_builtin
#define __has_builtin(x) 0
#endif

#define NPTS   131072
#define FCH    16
#define CSND   343.0f
#define PB     16           // points per pass
#define BLOCK  256          // 4 waves
#define GRID   768          // 3 WG/CU * 256 CUs, persistent
#define NBLK   (NPTS / PB)  // 8192

typedef _Float16 half8 __attribute__((ext_vector_type(8)));
typedef _Float16 half2v __attribute__((ext_vector_type(2)));
typedef float    f32x4 __attribute__((ext_vector_type(4)));

static __device__ __forceinline__ unsigned pack2(float a, float b) {
#if __has_builtin(__builtin_amdgcn_cvt_pkrtz)
  return __builtin_bit_cast(unsigned, __builtin_amdgcn_cvt_pkrtz(a, b));
#else
  half2v v; v[0] = (_Float16)a; v[1] = (_Float16)b;
  return __builtin_bit_cast(unsigned, v);
#endif
}

// tanh(x) = 1 - 2/(e^{2x}+1): 5 VALU ops, monotone-correct at +/-inf.
static __device__ __forceinline__ float mytanh(float x) {
#if __has_builtin(__builtin_amdgcn_exp2f)
  float e = __builtin_amdgcn_exp2f(2.885390082f * x);   // 2*log2(e)*x
#else
  float e = __expf(2.0f * x);
#endif
  return fmaf(-2.0f, __builtin_amdgcn_rcpf(e + 1.0f), 1.0f);
}

// Single-buffered 28 KB LDS -> 3 WG/CU with launch_bounds(256,3):
//   s_A[80][64] dw : A f16, rows R = v*16+p (v=0..4: h1,d0,d1,d2,c1; p=0..15),
//                    chunk c (4 dw = 8 units) stored at (c ^ p) -> b128, no conflicts
//   s_HG[16][128] dw: point p: h2 dwords [p*128..+63], G [p*128+64..+127].
//                    dword q = 16*w + col holds pack2(ntl=0, ntl=1) for that wave's
//                    j-pair; j(kappa)=32*(q>>4)+16*(kappa&1)+(q&15); chunks (q>>2)
//                    swizzled ^p. w3f rows permuted identically.
// Loop: { D(i-1) [waves 0,1] ; A(i) | b1 | loadX(i+1) ; B(i) ; C(i) | b2 }
// Hazards: A(i) wr s_A vs B(i-1) rd -> spans b2(i-1); B(i) rd vs A(i) wr -> b1(i);
//   C(i) wr s_HG vs D(i-1) rd -> b1(i); D(i) rd vs C(i) wr -> b2(i). Epilogue D
//   after final b2. All cross-wave pairs span >=1 barrier.

__global__ __launch_bounds__(BLOCK, 3) void helmholtz_kernel(
    const float* __restrict__ x,      // [N,3]
    const float* __restrict__ omega,  // [16]
    const float* __restrict__ W1,     // [3,128]
    const float* __restrict__ b1,     // [128]
    const float* __restrict__ W2,     // [128,128]
    const float* __restrict__ b2,     // [128]
    const float* __restrict__ W3,     // [128,32]
    const float* __restrict__ b3,     // [32]
    float* __restrict__ out)
{
  __shared__ unsigned s_A[80 * 64];    // 20 KB
  __shared__ unsigned s_HG[16 * 128];  //  8 KB

  const int tid  = threadIdx.x;
  const int w    = tid >> 6;   // wave 0..3
  const int l    = tid & 63;
  const int col  = l & 15;
  const int quad = l >> 4;
  const int nh   = w & 1;      // D: 0 = real cols, 1 = imag cols

  // ---- phase A task: point pA = tid>>4, units 8g..8g+7 ----
  const int pA = tid >> 4;
  const int g  = tid & 15;
  float wx[8], wy[8], wz[8], bB[8];
#pragma unroll
  for (int u = 0; u < 8; u++) {
    int unit = 8 * g + u;
    wx[u] = W1[unit]; wy[u] = W1[128 + unit]; wz[u] = W1[256 + unit];
    bB[u] = b1[unit];
  }

  // ---- W2^T fragments: n-tiles 2w, 2w+1 (32 VGPRs) ----
  half8 w2f[2][4];
#pragma unroll
  for (int ntl = 0; ntl < 2; ntl++) {
    const int n = 32 * w + 16 * ntl + col;
#pragma unroll
    for (int ks = 0; ks < 4; ks++) {
      half8 f;
#pragma unroll
      for (int j8 = 0; j8 < 8; j8++)
        f[j8] = (_Float16)W2[(ks * 32 + (quad << 3) + j8) * 128 + n];
      w2f[ntl][ks] = f;
    }
  }
  // ---- W3^T fragment, j-permuted to match HG layout (16 VGPRs) ----
  half8 w3f[4];
#pragma unroll
  for (int ks = 0; ks < 4; ks++) {
    half8 f;
#pragma unroll
    for (int j8 = 0; j8 < 8; j8++) {
      int kap = ks * 32 + (quad << 3) + j8;
      int q   = kap >> 1;
      int j   = 32 * (q >> 4) + 16 * (kap & 1) + (q & 15);
      f[j8] = (_Float16)W3[j * 32 + 16 * nh + col];
    }
    w3f[ks] = f;
  }

  const float b2r0 = b2[32 * w + col];
  const float b2r1 = b2[32 * w + 16 + col];
  float k2v = 0.0f;
  if (col >= 1) {
    float om = omega[col] * (1.0f / CSND);
    k2v = om * om;
  }
  const float b3v = b3[16 * nh + col];

  float wsum = 0.0f;
  float xr0, xr1, xr2;

  auto loadX = [&](int blk) {
    const float* xp = x + (size_t)(blk * PB + pA) * 3;
    xr0 = xp[0]; xr1 = xp[1]; xr2 = xp[2];
  };

  auto phaseA = [&]() {
    const int cbase = (g ^ pA) << 2;
    float t[8], s[8];
#pragma unroll
    for (int u = 0; u < 8; u++) {
      float z = fmaf(xr0, wx[u], fmaf(xr1, wy[u], fmaf(xr2, wz[u], bB[u])));
      t[u] = mytanh(z);
      s[u] = 1.0f - t[u] * t[u];
    }
    uint4 q;
    q = make_uint4(pack2(t[0], t[1]), pack2(t[2], t[3]),
                   pack2(t[4], t[5]), pack2(t[6], t[7]));
    *(uint4*)&s_A[(pA)      * 64 + cbase] = q;
    q = make_uint4(pack2(s[0]*wx[0], s[1]*wx[1]), pack2(s[2]*wx[2], s[3]*wx[3]),
                   pack2(s[4]*wx[4], s[5]*wx[5]), pack2(s[6]*wx[6], s[7]*wx[7]));
    *(uint4*)&s_A[(16 + pA) * 64 + cbase] = q;
    q = make_uint4(pack2(s[0]*wy[0], s[1]*wy[1]), pack2(s[2]*wy[2], s[3]*wy[3]),
                   pack2(s[4]*wy[4], s[5]*wy[5]), pack2(s[6]*wy[6], s[7]*wy[7]));
    *(uint4*)&s_A[(32 + pA) * 64 + cbase] = q;
    q = make_uint4(pack2(s[0]*wz[0], s[1]*wz[1]), pack2(s[2]*wz[2], s[3]*wz[3]),
                   pack2(s[4]*wz[4], s[5]*wz[5]), pack2(s[6]*wz[6], s[7]*wz[7]));
    *(uint4*)&s_A[(48 + pA) * 64 + cbase] = q;
    float c[8];
#pragma unroll
    for (int u = 0; u < 8; u++) {
      float wq = fmaf(wx[u], wx[u], fmaf(wy[u], wy[u], wz[u] * wz[u]));
      c[u] = -2.0f * t[u] * s[u] * wq;
    }
    q = make_uint4(pack2(c[0], c[1]), pack2(c[2], c[3]),
                   pack2(c[4], c[5]), pack2(c[6], c[7]));
    *(uint4*)&s_A[(64 + pA) * 64 + cbase] = q;
  };

  auto phaseDE = [&]() {
    const int pbase = col * 128;   // point row = col
    f32x4 dy = (f32x4){0.0f, 0.0f, 0.0f, 0.0f};
    f32x4 dl = (f32x4){0.0f, 0.0f, 0.0f, 0.0f};
#pragma unroll
    for (int ks = 0; ks < 4; ks++) {
      int pos = ((((ks << 2) + quad) ^ col) << 2);
      half8 afy = *(const half8*)&s_HG[pbase + pos];
      half8 afl = *(const half8*)&s_HG[pbase + 64 + pos];
      dy = __builtin_amdgcn_mfma_f32_16x16x32_f16(afy, w3f[ks], dy, 0, 0, 0);
      dl = __builtin_amdgcn_mfma_f32_16x16x32_f16(afl, w3f[ks], dl, 0, 0, 0);
    }
    if (col >= 1) {
#pragma unroll
      for (int r = 0; r < 4; r++) {
        float yv  = dy[r] + b3v;
        float res = fmaf(k2v, yv, dl[r]);
        wsum += res * res;
      }
    }
  };

  // ---- main loop ----
  loadX(blockIdx.x);
  bool first = true;
  for (int blk = blockIdx.x; blk < NBLK; blk += gridDim.x) {
    if (!first && w < 2) phaseDE();   // D(i-1): reads s_HG, pre-b1
    first = false;
    phaseA();                         // writes s_A
    __syncthreads();                  // b1

    int nblk = blk + (int)gridDim.x;
    if (nblk < NBLK) loadX(nblk);     // prefetch x for next pass

    // ---- B(i): [80 x 128] x [128 x 128]; wave w n-tiles 2w, 2w+1 ----
    f32x4 acc[5][2];
#pragma unroll
    for (int v = 0; v < 5; v++)
#pragma unroll
      for (int ntl = 0; ntl < 2; ntl++)
        acc[v][ntl] = (f32x4){0.0f, 0.0f, 0.0f, 0.0f};

#pragma unroll
    for (int v = 0; v < 5; v++) {
      const int rb = (v * 16 + col) * 64;
#pragma unroll
      for (int ks = 0; ks < 4; ks++) {
        half8 af = *(const half8*)&s_A[rb + ((((ks << 2) + quad) ^ col) << 2)];
        acc[v][0] = __builtin_amdgcn_mfma_f32_16x16x32_f16(af, w2f[0][ks], acc[v][0], 0, 0, 0);
        acc[v][1] = __builtin_amdgcn_mfma_f32_16x16x32_f16(af, w2f[1][ks], acc[v][1], 0, 0, 0);
      }
    }

    // ---- C(i): layer-2 elementwise; paired-dword writes into permuted HG ----
#pragma unroll
    for (int r = 0; r < 4; r++) {
      int p = (quad << 2) + r;
      float t2[2], gg[2];
#pragma unroll
      for (int ntl = 0; ntl < 2; ntl++) {
        float z2 = acc[0][ntl][r] + (ntl ? b2r1 : b2r0);
        float d0 = acc[1][ntl][r], d1 = acc[2][ntl][r], d2 = acc[3][ntl][r];
        float Av = acc[4][ntl][r];
        float t  = mytanh(z2);
        float s2 = 1.0f - t * t;
        t2[ntl] = t;
        gg[ntl] = s2 * (Av - 2.0f * t * (d0 * d0 + d1 * d1 + d2 * d2));
      }
      int q   = 16 * w + col;
      int pos = (((q >> 2) ^ p) << 2) + (q & 3);
      s_HG[p * 128 + pos]      = pack2(t2[0], t2[1]);
      s_HG[p * 128 + 64 + pos] = pack2(gg[0], gg[1]);
    }
    __syncthreads();                  // b2
  }
  if (w < 2) phaseDE();               // epilogue D for the final pass

  // ---- final: wave reduce, one atomic per wave ----
#pragma unroll
  for (int off = 32; off > 0; off >>= 1)
    wsum += __shfl_down(wsum, off, 64);
  if (l == 0)
    atomicAdd(out, wsum * (1.0f / ((float)NPTS * (float)(FCH - 1))));
}

extern "C" void kernel_launch(void* const* d_in, const int* in_sizes, int n_in,
                              void* d_out, int out_size, void* d_ws, size_t ws_size,
                              hipStream_t stream) {
  const float* x     = (const float*)d_in[0];
  const float* omega = (const float*)d_in[1];
  const float* W1    = (const float*)d_in[2];
  const float* b1    = (const float*)d_in[3];
  const float* W2    = (const float*)d_in[4];
  const float* b2    = (const float*)d_in[5];
  const float* W3    = (const float*)d_in[6];
  const float* b3    = (const float*)d_in[7];
  float* out = (float*)d_out;

  (void)hipMemsetAsync(out, 0, sizeof(float), stream);
  helmholtz_kernel<<<GRID, BLOCK, 0, stream>>>(x, omega, W1, b1, W2, b2, W3, b3, out);
}

// Round 12
// 120.726 us; speedup vs baseline: 1.0664x; 1.0664x over previous
//
#include <hip/hip_runtime.h>
#include <math.h>

#ifndef __has_builtin
#define __has_builtin(x) 0
#endif

#define NPTS   131072
#define FCH    16
#define CSND   343.0f
#define PB     16           // points per pass
#define BLOCK  256          // 4 waves
#define GRID   512          // 2 WG/CU * 256 CUs, persistent
#define NBLK   (NPTS / PB)  // 8192

typedef _Float16 half8 __attribute__((ext_vector_type(8)));
typedef _Float16 h2 __attribute__((ext_vector_type(2)));
typedef float    f32x4 __attribute__((ext_vector_type(4)));

static __device__ __forceinline__ h2 ph2(float a, float b) {
#if __has_builtin(__builtin_amdgcn_cvt_pkrtz)
  return __builtin_bit_cast(h2, __builtin_amdgcn_cvt_pkrtz(a, b));
#else
  h2 v; v[0] = (_Float16)a; v[1] = (_Float16)b;
  return v;
#endif
}
static __device__ __forceinline__ unsigned bc(h2 v) {
  return __builtin_bit_cast(unsigned, v);
}

// tanh(x) = 1 - 2/(e^{2x}+1): 5 VALU ops, monotone-correct at +/-inf.
static __device__ __forceinline__ float mytanh(float x) {
#if __has_builtin(__builtin_amdgcn_exp2f)
  float e = __builtin_amdgcn_exp2f(2.885390082f * x);   // 2*log2(e)*x
#else
  float e = __expf(2.0f * x);
#endif
  return fmaf(-2.0f, __builtin_amdgcn_rcpf(e + 1.0f), 1.0f);
}

// r8 skeleton (best, 60.8us) + packed-f16 elementwise + paired HG.
// LDS 56 KB -> 2 WG/CU:
//   s_A[2][80][64] dw : A f16, rows v*16+p, chunk c (8 units) at (c ^ p)
//   s_HG[2][16][128] dw: point p row; dword q=16w+col holds the (j, j+16) pair
//     with j = 32*(q>>4) + (q&15); h2-pair at swizzled pos, G-pair at pos+64.
//     chunk (q>>2) stored at ((q>>2) ^ p). w3f k-rows permuted identically:
//     kap -> j(kap) = 32*(q>>4) + 16*(kap&1) + (q&15), q = kap>>1.
// Per-pass (ONE barrier):
//   waves 0,1: D(i-1) reads HG[par^1] | all: A(i+1)->s_A[par^1] || B(i) reads
//   s_A[par], C(i)->HG[par] | bar.
// Hazards identical to r8 (proven): every cross-wave write->read spans >=1
// barrier via double buffering of both s_A and s_HG.

__global__ __launch_bounds__(BLOCK, 2) void helmholtz_kernel(
    const float* __restrict__ x,      // [N,3]
    const float* __restrict__ omega,  // [16]
    const float* __restrict__ W1,     // [3,128]
    const float* __restrict__ b1,     // [128]
    const float* __restrict__ W2,     // [128,128]
    const float* __restrict__ b2,     // [128]
    const float* __restrict__ W3,     // [128,32]
    const float* __restrict__ b3,     // [32]
    float* __restrict__ out)
{
  __shared__ unsigned s_A[2][80 * 64];    // 40 KB
  __shared__ unsigned s_HG[2][16 * 128];  // 16 KB

  const int tid  = threadIdx.x;
  const int w    = tid >> 6;   // wave 0..3
  const int l    = tid & 63;
  const int col  = l & 15;
  const int quad = l >> 4;
  const int nh   = w & 1;      // D: 0 = real cols, 1 = imag cols

  // ---- phase A: point pA = tid>>4, unit pairs (8g+2u2, 8g+2u2+1), packed f16 ----
  const int pA = tid >> 4;
  const int g  = tid & 15;
  h2 wx2[4], wy2[4], wz2[4], bB2[4], m2wq2[4];
#pragma unroll
  for (int u2 = 0; u2 < 4; u2++) {
    int u0 = 8 * g + 2 * u2, u1 = u0 + 1;
    float ax = W1[u0], ay = W1[128 + u0], az = W1[256 + u0];
    float bx = W1[u1], by = W1[128 + u1], bz = W1[256 + u1];
    wx2[u2] = ph2(ax, bx); wy2[u2] = ph2(ay, by); wz2[u2] = ph2(az, bz);
    bB2[u2] = ph2(b1[u0], b1[u1]);
    m2wq2[u2] = ph2(-2.0f * (ax * ax + ay * ay + az * az),
                    -2.0f * (bx * bx + by * by + bz * bz));
  }

  // ---- W2^T fragments: n-tiles 2w, 2w+1 (32 VGPRs) ----
  half8 w2f[2][4];
#pragma unroll
  for (int ntl = 0; ntl < 2; ntl++) {
    const int n = 32 * w + 16 * ntl + col;
#pragma unroll
    for (int ks = 0; ks < 4; ks++) {
      half8 f;
#pragma unroll
      for (int j8 = 0; j8 < 8; j8++)
        f[j8] = (_Float16)W2[(ks * 32 + (quad << 3) + j8) * 128 + n];
      w2f[ntl][ks] = f;
    }
  }
  // ---- W3^T fragment, k-permuted to match paired HG layout (16 VGPRs) ----
  half8 w3f[4];
#pragma unroll
  for (int ks = 0; ks < 4; ks++) {
    half8 f;
#pragma unroll
    for (int j8 = 0; j8 < 8; j8++) {
      int kap = ks * 32 + (quad << 3) + j8;
      int q   = kap >> 1;
      int j   = 32 * (q >> 4) + 16 * (kap & 1) + (q & 15);
      f[j8] = (_Float16)W3[j * 32 + 16 * nh + col];
    }
    w3f[ks] = f;
  }

  const float b2r0 = b2[32 * w + col];
  const float b2r1 = b2[32 * w + 16 + col];
  float k2v = 0.0f;
  if (col >= 1) {
    float om = omega[col] * (1.0f / CSND);
    k2v = om * om;
  }
  const float b3v = b3[16 * nh + col];
  const h2 one2 = {(_Float16)1.0f, (_Float16)1.0f};
  const h2 m2c  = {(_Float16)-2.0f, (_Float16)-2.0f};

  float wsum = 0.0f;

  // ---- phase A: packed f16, 5 ds_write_b128 ----
  auto phaseA = [&](int blk, int buf) {
    const float* xp = x + (size_t)(blk * PB + pA) * 3;
    float x0 = xp[0], x1 = xp[1], x2 = xp[2];
    h2 xh0 = ph2(x0, x0), xh1 = ph2(x1, x1), xh2 = ph2(x2, x2);
    h2 tp[4], sp[4];
#pragma unroll
    for (int u2 = 0; u2 < 4; u2++) {
      h2 z = xh0 * wx2[u2] + xh1 * wy2[u2] + xh2 * wz2[u2] + bB2[u2];
      float t0 = mytanh((float)z[0]);
      float t1 = mytanh((float)z[1]);
      tp[u2] = ph2(t0, t1);
      sp[u2] = one2 - tp[u2] * tp[u2];
    }
    unsigned* sA = s_A[buf];
    const int cbase = (g ^ pA) << 2;
    uint4 q;
    q = make_uint4(bc(tp[0]), bc(tp[1]), bc(tp[2]), bc(tp[3]));
    *(uint4*)&sA[(pA)      * 64 + cbase] = q;
    q = make_uint4(bc(sp[0]*wx2[0]), bc(sp[1]*wx2[1]), bc(sp[2]*wx2[2]), bc(sp[3]*wx2[3]));
    *(uint4*)&sA[(16 + pA) * 64 + cbase] = q;
    q = make_uint4(bc(sp[0]*wy2[0]), bc(sp[1]*wy2[1]), bc(sp[2]*wy2[2]), bc(sp[3]*wy2[3]));
    *(uint4*)&sA[(32 + pA) * 64 + cbase] = q;
    q = make_uint4(bc(sp[0]*wz2[0]), bc(sp[1]*wz2[1]), bc(sp[2]*wz2[2]), bc(sp[3]*wz2[3]));
    *(uint4*)&sA[(48 + pA) * 64 + cbase] = q;
    q = make_uint4(bc((tp[0]*sp[0])*m2wq2[0]), bc((tp[1]*sp[1])*m2wq2[1]),
                   bc((tp[2]*sp[2])*m2wq2[2]), bc((tp[3]*sp[3])*m2wq2[3]));
    *(uint4*)&sA[(64 + pA) * 64 + cbase] = q;
  };

  // ---- phase D+E (waves 0,1): paired-b128 reads, residual in regs ----
  auto phaseDE = [&](int buf) {
    const unsigned* hgb = s_HG[buf];
    const int pbase = col * 128;   // A-operand row m = point = col
    f32x4 dy = (f32x4){0.0f, 0.0f, 0.0f, 0.0f};
    f32x4 dl = (f32x4){0.0f, 0.0f, 0.0f, 0.0f};
#pragma unroll
    for (int ks = 0; ks < 4; ks++) {
      int pos = ((((ks << 2) + quad) ^ col) << 2);
      half8 afy = *(const half8*)&hgb[pbase + pos];
      half8 afl = *(const half8*)&hgb[pbase + 64 + pos];
      dy = __builtin_amdgcn_mfma_f32_16x16x32_f16(afy, w3f[ks], dy, 0, 0, 0);
      dl = __builtin_amdgcn_mfma_f32_16x16x32_f16(afl, w3f[ks], dl, 0, 0, 0);
    }
    if (col >= 1) {
#pragma unroll
      for (int r = 0; r < 4; r++) {
        float yv  = dy[r] + b3v;
        float res = fmaf(k2v, yv, dl[r]);
        wsum += res * res;
      }
    }
  };

  // ---- prologue ----
  phaseA(blockIdx.x, 0);
  __syncthreads();

  int parity = 0;
  for (int blk = blockIdx.x; blk < NBLK; blk += gridDim.x, parity ^= 1) {
    // D(i-1)+E(i-1): waves 0,1; reads HG[parity^1] (pre-barrier region)
    if (w < 2 && blk != (int)blockIdx.x) phaseDE(parity ^ 1);

    // A(i+1): packed VALU, independent of B(i) below
    int nblk = blk + (int)gridDim.x;
    if (nblk < NBLK) phaseA(nblk, parity ^ 1);

    // B(i): [80x128]x[128x128] from s_A[parity]; wave w n-tiles 2w,2w+1
    const unsigned* sA = s_A[parity];
    f32x4 acc[5][2];
#pragma unroll
    for (int v = 0; v < 5; v++)
#pragma unroll
      for (int ntl = 0; ntl < 2; ntl++)
        acc[v][ntl] = (f32x4){0.0f, 0.0f, 0.0f, 0.0f};

#pragma unroll
    for (int v = 0; v < 5; v++) {
      const int rb = (v * 16 + col) * 64;
#pragma unroll
      for (int ks = 0; ks < 4; ks++) {
        half8 af = *(const half8*)&sA[rb + ((((ks << 2) + quad) ^ col) << 2)];
        acc[v][0] = __builtin_amdgcn_mfma_f32_16x16x32_f16(af, w2f[0][ks], acc[v][0], 0, 0, 0);
        acc[v][1] = __builtin_amdgcn_mfma_f32_16x16x32_f16(af, w2f[1][ks], acc[v][1], 0, 0, 0);
      }
    }

    // C(i): packed-f16 layer-2 elementwise -> paired writes into HG[parity]
    {
      unsigned* hg = s_HG[parity];
#pragma unroll
      for (int r = 0; r < 4; r++) {
        int p = (quad << 2) + r;
        float t0 = mytanh(acc[0][0][r] + b2r0);
        float t1 = mytanh(acc[0][1][r] + b2r1);
        h2 tp = ph2(t0, t1);
        h2 sp = one2 - tp * tp;
        h2 d0 = ph2(acc[1][0][r], acc[1][1][r]);
        h2 d1 = ph2(acc[2][0][r], acc[2][1][r]);
        h2 d2 = ph2(acc[3][0][r], acc[3][1][r]);
        h2 Ap = ph2(acc[4][0][r], acc[4][1][r]);
        h2 Bp = d0 * d0 + d1 * d1 + d2 * d2;
        h2 gg = sp * (Ap + m2c * (tp * Bp));
        int q   = 16 * w + col;
        int pos = (((q >> 2) ^ p) << 2) + (q & 3);
        hg[p * 128 + pos]      = bc(tp);
        hg[p * 128 + 64 + pos] = bc(gg);
      }
    }
    __syncthreads();  // the ONE barrier per pass
  }

  // epilogue: D+E for the final pass
  if (w < 2) phaseDE(parity ^ 1);

  // ---- final: wave reduce, one atomic per wave ----
#pragma unroll
  for (int off = 32; off > 0; off >>= 1)
    wsum += __shfl_down(wsum, off, 64);
  if (l == 0)
    atomicAdd(out, wsum * (1.0f / ((float)NPTS * (float)(FCH - 1))));
}

extern "C" void kernel_launch(void* const* d_in, const int* in_sizes, int n_in,
                              void* d_out, int out_size, void* d_ws, size_t ws_size,
                              hipStream_t stream) {
  const float* x     = (const float*)d_in[0];
  const float* omega = (const float*)d_in[1];
  const float* W1    = (const float*)d_in[2];
  const float* b1    = (const float*)d_in[3];
  const float* W2    = (const float*)d_in[4];
  const float* b2    = (const float*)d_in[5];
  const float* W3    = (const float*)d_in[6];
  const float* b3    = (const float*)d_in[7];
  float* out = (float*)d_out;

  (void)hipMemsetAsync(out, 0, sizeof(float), stream);
  helmholtz_kernel<<<GRID, BLOCK, 0, stream>>>(x, omega, W1, b1, W2, b2, W3, b3, out);
}